// Round 1
// baseline (1353.344 us; speedup 1.0000x reference)
//
#include <hip/hip_runtime.h>

#define B_ 64
#define Q_ 64
#define L_ 8192
#define KCONV 51      // narrow conv kernel size
#define HC 26         // raw half params
#define KTRANS 501    // transpose-conv kernel size
#define HT 251        // raw half params
#define TILE 1024
#define NTILE (L_ / TILE)      // 8
#define NY (TILE + 500)        // 1524 softmax values needed per tile
#define NW (TILE + 550)        // 1574 x values needed per tile
#define KTP 504                // padded kt row (16B-aligned rows)

// workspace layout (float offsets)
#define WS_KC 0
#define WS_A 64
#define WS_SCALE 128
#define WS_KT 192
#define WS_STATS (WS_KT + Q_ * KTP)   // [B*Q][2] = {rowmax, 1/sumexp}

// pad every 32 floats by 1 to break power-of-2 LDS bank strides
#define PADI(i) ((i) + ((i) >> 5))

__device__ __forceinline__ float sigm(float v) {
    return 1.0f / (1.0f + __expf(-v));
}

// ---------------- kernel 1: derived parameters ----------------
__global__ __launch_bounds__(256) void k_params(const float* __restrict__ cwh,
                                                const float* __restrict__ tcw,
                                                const float* __restrict__ araw,
                                                float* __restrict__ ws) {
    int tid = threadIdx.x;
    // symmetric 51-tap kernel: kc[j] = w[min(j, 50-j)]
    if (tid < KCONV) ws[WS_KC + tid] = cwh[tid < HC ? tid : (KCONV - 1 - tid)];
    if (tid < Q_) ws[WS_A + tid] = sigm(araw[tid]);
    // kt[q][j] = sigmoid(tc[q][j<=250 ? j : 500-j]), rows padded to 504
    for (int idx = tid; idx < Q_ * KTP; idx += 256) {
        int q = idx / KTP, j = idx - q * KTP;
        float v = 0.0f;
        if (j < KTRANS) {
            int h = (j <= 250) ? j : (500 - j);
            v = sigm(tcw[q * HT + h]);
        }
        ws[WS_KT + idx] = v;
    }
    __syncthreads();
    if (tid == 0) {
        float p = 1.0f;
        for (int q = 0; q < Q_; q++) p *= ws[WS_A + q];
        float peak = sigm(tcw[(Q_ - 1) * HT + 250]);  // wt[-1,-1] (kernel center)
        ws[WS_SCALE] = 1.0f / (peak * p);
    }
}

// ---------------- kernel 2: per-row softmax stats (max, 1/sum) ----------------
// one block per (b,q) row; conv51 computed with sliding-window registers
__global__ __launch_bounds__(256) void k_stats(const float* __restrict__ x,
                                               float* __restrict__ ws) {
    const int bq = blockIdx.x;
    const int tid = threadIdx.x;
    __shared__ float xp[PADI(L_ + 49) + 1];   // x row padded by 25 zeros each side
    __shared__ float red[8];
    const float* xrow = x + (size_t)bq * L_;
    const float* kc = ws + WS_KC;             // uniform -> scalar loads
    for (int i = tid; i < L_ + 50; i += 256) {
        int xi = i - 25;
        xp[PADI(i)] = (xi >= 0 && xi < L_) ? xrow[xi] : 0.0f;
    }
    __syncthreads();
    float y[32];
    const int base = tid * 32;   // 256 threads * 32 = 8192
    #pragma unroll
    for (int c = 0; c < 32; c += 8) {
        float acc[8] = {0, 0, 0, 0, 0, 0, 0, 0};
        float w[8];
        #pragma unroll
        for (int i = 0; i < 7; i++) w[i] = xp[PADI(base + c + i)];
        #pragma unroll
        for (int m = 0; m < KCONV; m++) {
            w[7] = xp[PADI(base + c + m + 7)];
            float k = kc[m];
            #pragma unroll
            for (int i = 0; i < 8; i++) acc[i] = fmaf(w[i], k, acc[i]);
            #pragma unroll
            for (int i = 0; i < 7; i++) w[i] = w[i + 1];
        }
        #pragma unroll
        for (int i = 0; i < 8; i++) y[c + i] = acc[i];
    }
    float mx = -3.402823466e+38f;
    #pragma unroll
    for (int i = 0; i < 32; i++) mx = fmaxf(mx, y[i]);
    #pragma unroll
    for (int o = 32; o > 0; o >>= 1) mx = fmaxf(mx, __shfl_xor(mx, o));
    if ((tid & 63) == 0) red[tid >> 6] = mx;
    __syncthreads();
    mx = fmaxf(fmaxf(red[0], red[1]), fmaxf(red[2], red[3]));
    float sm = 0.0f;
    #pragma unroll
    for (int i = 0; i < 32; i++) sm += __expf(y[i] - mx);
    #pragma unroll
    for (int o = 32; o > 0; o >>= 1) sm += __shfl_xor(sm, o);
    if ((tid & 63) == 0) red[4 + (tid >> 6)] = sm;
    __syncthreads();
    if (tid == 0) {
        float s = red[4] + red[5] + red[6] + red[7];
        ws[WS_STATS + bq * 2 + 0] = mx;
        ws[WS_STATS + bq * 2 + 1] = 1.0f / s;
    }
}

// ---------------- kernel 3: fused conv51 -> softmax -> conv501 -> lattice ----------------
// block = (l-tile of 1024, b); loops q serially keeping lattice state (r, t2) in registers
__global__ __launch_bounds__(256) void k_main(const float* __restrict__ x,
                                              const float* __restrict__ ws,
                                              float* __restrict__ out) {
    const int tid = threadIdx.x;
    const int l0 = blockIdx.x * TILE;
    const int b = blockIdx.y;
    __shared__ float xw[PADI(NW - 1) + 1];   // x window [l0-275, l0+TILE+275)
    __shared__ float sl[PADI(NY - 1) + 1];   // softmax values [l0-250, l0+TILE+250)

    const float* kc  = ws + WS_KC;                    // uniform -> s_load
    const float* al  = ws + WS_A;                     // uniform
    const float* stl = ws + WS_STATS + b * 2 * Q_;    // uniform
    const float inv_scale = ws[WS_SCALE];

    float r0 = 0, r1 = 0, r2 = 0, r3 = 0;
    float t20 = 1, t21 = 1, t22 = 1, t23 = 1;
    const int t4 = tid * 4;
    const int ybase = tid * 6;   // 254 threads * 6 = 1524 = NY exactly

    for (int q = 0; q < Q_; q++) {
        __syncthreads();  // protect xw/sl from previous iteration's readers
        const float* xrow = x + (size_t)(b * Q_ + q) * L_;
        const int wl0 = l0 - 275;
        for (int i = tid; i < NW; i += 256) {
            int xi = wl0 + i;
            xw[PADI(i)] = (xi >= 0 && xi < L_) ? xrow[xi] : 0.0f;
        }
        __syncthreads();
        const float mx = stl[2 * q], isum = stl[2 * q + 1];
        // conv51 + exp-normalize into sl (sliding window, 6 outputs/thread)
        if (ybase < NY) {
            float acc[6] = {0, 0, 0, 0, 0, 0};
            float w[6];
            #pragma unroll
            for (int i = 0; i < 5; i++) w[i] = xw[PADI(ybase + i)];
            #pragma unroll
            for (int m = 0; m < KCONV; m++) {
                w[5] = xw[PADI(ybase + m + 5)];
                float k = kc[m];
                #pragma unroll
                for (int i = 0; i < 6; i++) acc[i] = fmaf(w[i], k, acc[i]);
                #pragma unroll
                for (int i = 0; i < 5; i++) w[i] = w[i + 1];
            }
            #pragma unroll
            for (int i = 0; i < 6; i++) {
                int j = ybase + i;
                int l = l0 - 250 + j;
                float v = 0.0f;
                if (l >= 0 && l < L_) v = __expf(acc[i] - mx) * isum;
                sl[PADI(j)] = v;
            }
        }
        __syncthreads();
        // conv501: 4 contiguous outputs/thread, rotating 4-register window,
        // kernel taps via uniform (scalar) float4 loads from global ws
        const float* ktg = ws + WS_KT + q * KTP;
        float w0 = sl[PADI(t4 + 0)];
        float w1 = sl[PADI(t4 + 1)];
        float w2 = sl[PADI(t4 + 2)];
        float w3;
        float z0 = 0, z1 = 0, z2 = 0, z3 = 0;
        for (int mm = 0; mm < 500; mm += 4) {
            const float4 kv = *(const float4*)(ktg + mm);
            w3 = sl[PADI(t4 + mm + 3)];
            z0 = fmaf(w0, kv.x, z0); z1 = fmaf(w1, kv.x, z1);
            z2 = fmaf(w2, kv.x, z2); z3 = fmaf(w3, kv.x, z3);
            w0 = sl[PADI(t4 + mm + 4)];
            z0 = fmaf(w1, kv.y, z0); z1 = fmaf(w2, kv.y, z1);
            z2 = fmaf(w3, kv.y, z2); z3 = fmaf(w0, kv.y, z3);
            w1 = sl[PADI(t4 + mm + 5)];
            z0 = fmaf(w2, kv.z, z0); z1 = fmaf(w3, kv.z, z1);
            z2 = fmaf(w0, kv.z, z2); z3 = fmaf(w1, kv.z, z3);
            w2 = sl[PADI(t4 + mm + 6)];
            z0 = fmaf(w3, kv.w, z0); z1 = fmaf(w0, kv.w, z1);
            z2 = fmaf(w1, kv.w, z2); z3 = fmaf(w2, kv.w, z3);
        }
        {   // tail tap m = 500
            const float k = ktg[500];
            w3 = sl[PADI(t4 + 503)];
            z0 = fmaf(w0, k, z0); z1 = fmaf(w1, k, z1);
            z2 = fmaf(w2, k, z2); z3 = fmaf(w3, k, z3);
        }
        // lattice recursion step for channel q
        const float aq = al[q];
        {
            float rn = z0, tn = 1.0f - rn;
            float si = 1.0f / (1.0f - aq * r0 * rn);
            float rnew = r0 + aq * rn * t20 * si;
            t20 = aq * t20 * tn * tn * si * si; r0 = rnew;
        }
        {
            float rn = z1, tn = 1.0f - rn;
            float si = 1.0f / (1.0f - aq * r1 * rn);
            float rnew = r1 + aq * rn * t21 * si;
            t21 = aq * t21 * tn * tn * si * si; r1 = rnew;
        }
        {
            float rn = z2, tn = 1.0f - rn;
            float si = 1.0f / (1.0f - aq * r2 * rn);
            float rnew = r2 + aq * rn * t22 * si;
            t22 = aq * t22 * tn * tn * si * si; r2 = rnew;
        }
        {
            float rn = z3, tn = 1.0f - rn;
            float si = 1.0f / (1.0f - aq * r3 * rn);
            float rnew = r3 + aq * rn * t23 * si;
            t23 = aq * t23 * tn * tn * si * si; r3 = rnew;
        }
    }
    float4 o;
    o.x = r0 * inv_scale;
    o.y = r1 * inv_scale;
    o.z = r2 * inv_scale;
    o.w = r3 * inv_scale;
    *(float4*)&out[(size_t)b * L_ + l0 + t4] = o;
}

extern "C" void kernel_launch(void* const* d_in, const int* in_sizes, int n_in,
                              void* d_out, int out_size, void* d_ws, size_t ws_size,
                              hipStream_t stream) {
    (void)in_sizes; (void)n_in; (void)out_size; (void)ws_size;
    const float* x    = (const float*)d_in[0];
    const float* cwh  = (const float*)d_in[1];
    const float* tcw  = (const float*)d_in[2];
    const float* araw = (const float*)d_in[3];
    float* out = (float*)d_out;
    float* ws  = (float*)d_ws;

    hipLaunchKernelGGL(k_params, dim3(1), dim3(256), 0, stream, cwh, tcw, araw, ws);
    hipLaunchKernelGGL(k_stats, dim3(B_ * Q_), dim3(256), 0, stream, x, ws);
    hipLaunchKernelGGL(k_main, dim3(NTILE, B_), dim3(256), 0, stream, x, ws, out);
}

// Round 2
// 195.121 us; speedup vs baseline: 6.9359x; 6.9359x over previous
//
#include <hip/hip_runtime.h>

#define B_ 64
#define Q_ 64
#define L_ 8192
#define KCONV 51
#define HC 26
#define HT 251

// ---- workspace layout (bytes) ----
// PAR (floats): a[0..63], scale at [64], kc at [80..130]
#define TA_OFF 4096
// TA: [q][c][lane] -> 8 halves (16 B). 64 q * 17 c * 64 lanes * 16 B = 1,114,112 B
#define S_OFF  2097152
#define RSB    17472          // S row stride bytes = 8736 halves (LP 256 + 8192 + 288)
// S total: 4096 rows * 17472 B = 71,565,312 B  (ws end ~73.7 MB)

#define NCH 17                // K-chunks of 32 covering 501 taps (with -6 shift)
#define PADI(i) ((i) + ((i) >> 5))
#define SWZB(a) ((a) ^ ((((a) >> 7) & 3) << 5))

typedef _Float16 f16x8 __attribute__((ext_vector_type(8)));
typedef float f32x4 __attribute__((ext_vector_type(4)));

__device__ __forceinline__ float sigm(float v) {
    return 1.0f / (1.0f + __expf(-v));
}

// ---------------- kernel 1: derived parameters + Toeplitz kernel table ----------------
// blocks 0..63: build TA[q];  block 64: a[], kc[], scale
__global__ __launch_bounds__(256) void k_params(const float* __restrict__ cwh,
                                                const float* __restrict__ tcw,
                                                const float* __restrict__ araw,
                                                float* __restrict__ ws) {
    const int tid = threadIdx.x;
    const int q = blockIdx.x;
    char* wsb = (char*)ws;
    if (q < Q_) {
        // TA[q][c][lane][jj] = kt_q[32c + 8*(lane>>4) + jj - (lane&15) - 6]
        for (int idx = tid; idx < NCH * 64; idx += 256) {
            int c = idx >> 6, lane = idx & 63;
            int g = lane >> 4, i = lane & 15;
            int mbase = 32 * c + 8 * g - i - 6;
            f16x8 hv;
            #pragma unroll
            for (int jj = 0; jj < 8; jj++) {
                int m = mbase + jj;
                float v = 0.0f;
                if (m >= 0 && m <= 500) {
                    int hh = (m <= 250) ? m : (500 - m);
                    v = sigm(tcw[q * HT + hh]);
                }
                hv[jj] = (_Float16)v;
            }
            *(f16x8*)(wsb + TA_OFF + ((size_t)q * (NCH * 64) + idx) * 16) = hv;
        }
    } else {
        if (tid < Q_) ws[tid] = sigm(araw[tid]);
        if (tid < KCONV) ws[80 + tid] = cwh[tid < HC ? tid : (KCONV - 1 - tid)];
        __syncthreads();
        if (tid == 0) {
            float p = 1.0f;
            for (int j = 0; j < Q_; j++) p *= ws[j];
            float peak = sigm(tcw[(Q_ - 1) * HT + 250]);
            ws[64] = 1.0f / (peak * p);
        }
    }
}

// ---------------- kernel 2: conv51 + softmax, store S as padded f16 rows ----------------
// one block per (b,q) row
__global__ __launch_bounds__(256) void k_soft(const float* __restrict__ x,
                                              float* __restrict__ ws) {
    const int bq = blockIdx.x;
    const int tid = threadIdx.x;
    __shared__ float xp[PADI(L_ + 49) + 1];
    __shared__ float red[8];
    char* wsb = (char*)ws;
    char* row = wsb + S_OFF + (size_t)bq * RSB;

    // zero the row pads (left 512 B, right 576 B) every call
    const uint4 z4 = {0u, 0u, 0u, 0u};
    if (tid < 32) ((uint4*)row)[tid] = z4;
    else if (tid >= 64 && tid < 100) *(uint4*)(row + 16896 + 16 * (tid - 64)) = z4;

    const float* xrow = x + (size_t)bq * L_;
    const float* kc = ws + 80;               // uniform -> scalar loads
    for (int i = tid; i < L_ + 50; i += 256) {
        int xi = i - 25;
        xp[PADI(i)] = (xi >= 0 && xi < L_) ? xrow[xi] : 0.0f;
    }
    __syncthreads();
    float y[32];
    const int base = tid * 32;
    #pragma unroll
    for (int c = 0; c < 32; c += 8) {
        float acc[8] = {0, 0, 0, 0, 0, 0, 0, 0};
        float w[8];
        #pragma unroll
        for (int i = 0; i < 7; i++) w[i] = xp[PADI(base + c + i)];
        #pragma unroll
        for (int m = 0; m < KCONV; m++) {
            w[7] = xp[PADI(base + c + m + 7)];
            float k = kc[m];
            #pragma unroll
            for (int i = 0; i < 8; i++) acc[i] = fmaf(w[i], k, acc[i]);
            #pragma unroll
            for (int i = 0; i < 7; i++) w[i] = w[i + 1];
        }
        #pragma unroll
        for (int i = 0; i < 8; i++) y[c + i] = acc[i];
    }
    float mx = -3.402823466e+38f;
    #pragma unroll
    for (int i = 0; i < 32; i++) mx = fmaxf(mx, y[i]);
    #pragma unroll
    for (int o = 32; o > 0; o >>= 1) mx = fmaxf(mx, __shfl_xor(mx, o));
    if ((tid & 63) == 0) red[tid >> 6] = mx;
    __syncthreads();
    mx = fmaxf(fmaxf(red[0], red[1]), fmaxf(red[2], red[3]));
    float sm = 0.0f;
    #pragma unroll
    for (int i = 0; i < 32; i++) sm += __expf(y[i] - mx);
    #pragma unroll
    for (int o = 32; o > 0; o >>= 1) sm += __shfl_xor(sm, o);
    if ((tid & 63) == 0) red[4 + (tid >> 6)] = sm;
    __syncthreads();
    const float isum = 1.0f / (red[4] + red[5] + red[6] + red[7]);
    // store 32 normalized f16 values per thread (64 B, 16B-aligned)
    char* dst = row + 512 + 64 * tid;
    #pragma unroll
    for (int k = 0; k < 4; k++) {
        f16x8 hv;
        #pragma unroll
        for (int j = 0; j < 8; j++)
            hv[j] = (_Float16)(__expf(y[8 * k + j] - mx) * isum);
        *(f16x8*)(dst + 16 * k) = hv;
    }
}

// ---------------- kernel 3: MFMA banded-Toeplitz conv501 + lattice ----------------
// grid (8 l-tiles, 64 b), 256 threads = 4 waves; each wave owns a 16x16 output tile per q
__global__ __launch_bounds__(256) void k_conv(const float* __restrict__ ws,
                                              float* __restrict__ out) {
    const int tid = threadIdx.x;
    const int w = tid >> 6, lane = tid & 63;
    const int g = lane >> 4, n = lane & 15;
    const int b = blockIdx.y, l0 = blockIdx.x * 1024;
    const char* wsb = (const char*)ws;
    __shared__ uint4 S_lds[200];            // 3200 B (1552 staged halves + swizzle room)
    char* sl = (char*)S_lds;

    // precomputed swizzled B-fragment LDS byte addresses (per lane, q-invariant)
    int bofs[NCH];
    #pragma unroll
    for (int c = 0; c < NCH; c++) {
        int a0 = 512 * w + 64 * c + 32 * n + 16 * g;
        bofs[c] = SWZB(a0);
    }
    const int wr = SWZB(16 * tid);

    float r0 = 0, r1 = 0, r2 = 0, r3 = 0;
    float t20 = 1, t21 = 1, t22 = 1, t23 = 1;
    const float inv_scale = ws[64];

    // prefetch q=0 S tile into regs: LDS[half i] = S[l0-256+i], i in [0,1552)
    uint4 stg;
    if (tid < 194)
        stg = *(const uint4*)(wsb + S_OFF + (size_t)(b * Q_) * RSB + 2 * l0 + 16 * tid);

    for (int q = 0; q < Q_; q++) {
        __syncthreads();                     // previous q's readers done
        if (tid < 194) *(uint4*)(sl + wr) = stg;
        __syncthreads();
        if (q < Q_ - 1 && tid < 194)         // prefetch next tile under MFMA phase
            stg = *(const uint4*)(wsb + S_OFF + (size_t)(b * Q_ + q + 1) * RSB + 2 * l0 + 16 * tid);

        const char* tab = wsb + TA_OFF + ((size_t)q * (NCH * 64) + lane) * 16;
        f32x4 acc = {0.0f, 0.0f, 0.0f, 0.0f};
        #pragma unroll
        for (int c = 0; c < NCH; c++) {
            f16x8 af = *(const f16x8*)(tab + c * 1024);       // Toeplitz kernel frag (L2-hot)
            f16x8 bf = *(const f16x8*)(sl + bofs[c]);          // data frag (ds_read_b128)
            acc = __builtin_amdgcn_mfma_f32_16x16x32_f16(af, bf, acc, 0, 0, 0);
        }
        const float aq = ws[q];
        {   float rn = acc[0], tn = 1.0f - rn;
            float si = 1.0f / (1.0f - aq * r0 * rn);
            float rnew = r0 + aq * rn * t20 * si;
            t20 = aq * t20 * tn * tn * si * si; r0 = rnew; }
        {   float rn = acc[1], tn = 1.0f - rn;
            float si = 1.0f / (1.0f - aq * r1 * rn);
            float rnew = r1 + aq * rn * t21 * si;
            t21 = aq * t21 * tn * tn * si * si; r1 = rnew; }
        {   float rn = acc[2], tn = 1.0f - rn;
            float si = 1.0f / (1.0f - aq * r2 * rn);
            float rnew = r2 + aq * rn * t22 * si;
            t22 = aq * t22 * tn * tn * si * si; r2 = rnew; }
        {   float rn = acc[3], tn = 1.0f - rn;
            float si = 1.0f / (1.0f - aq * r3 * rn);
            float rnew = r3 + aq * rn * t23 * si;
            t23 = aq * t23 * tn * tn * si * si; r3 = rnew; }
    }
    // D layout: col = lane&15 (=n), row = 4*(lane>>4)+reg -> l = l0+256w+16n+4g+reg
    const int lbase = l0 + 256 * w + 16 * n + 4 * g;
    float4 o;
    o.x = r0 * inv_scale; o.y = r1 * inv_scale;
    o.z = r2 * inv_scale; o.w = r3 * inv_scale;
    *(float4*)&out[(size_t)b * L_ + lbase] = o;
}

extern "C" void kernel_launch(void* const* d_in, const int* in_sizes, int n_in,
                              void* d_out, int out_size, void* d_ws, size_t ws_size,
                              hipStream_t stream) {
    (void)in_sizes; (void)n_in; (void)out_size; (void)ws_size;
    const float* x    = (const float*)d_in[0];
    const float* cwh  = (const float*)d_in[1];
    const float* tcw  = (const float*)d_in[2];
    const float* araw = (const float*)d_in[3];
    float* out = (float*)d_out;
    float* ws  = (float*)d_ws;

    hipLaunchKernelGGL(k_params, dim3(Q_ + 1), dim3(256), 0, stream, cwh, tcw, araw, ws);
    hipLaunchKernelGGL(k_soft, dim3(B_ * Q_), dim3(256), 0, stream, x, ws);
    hipLaunchKernelGGL(k_conv, dim3(8, B_), dim3(256), 0, stream, ws, out);
}